// Round 1
// baseline (406.913 us; speedup 1.0000x reference)
//
#include <hip/hip_runtime.h>

#define WAVE 64
static __device__ __forceinline__ float lrelu(float x) { return x >= 0.f ? x : 0.2f * x; }

// ---------------- GEMM: H[N][128] = X[N][128] @ W[128][128], f32, K-split LDS ----------------
__global__ __launch_bounds__(256) void gemm128_kernel(const float* __restrict__ X,
                                                      const float* __restrict__ W,
                                                      float* __restrict__ H, int N) {
    __shared__ float Ws[64 * 128];   // 32 KB (half of W)
    __shared__ float Xs[16 * 128];   // 8 KB (16 node rows)
    int tid = threadIdx.x;
    long base = (long)blockIdx.x * 16;
    float4* Ws4 = (float4*)Ws;
    float4* Xs4 = (float4*)Xs;
    const float4* X4 = (const float4*)(X + base * 128);
    for (int i = tid; i < 512; i += 256) Xs4[i] = X4[i];
    int fgrp = tid & 31;        // feature float4 index (0..31)
    int n0 = (tid >> 5) * 2;    // local node pair
    float4 acc0 = {0, 0, 0, 0}, acc1 = {0, 0, 0, 0};
    for (int half = 0; half < 2; ++half) {
        __syncthreads();  // Xs ready (half0) / previous compute done (half1)
        const float4* W4 = (const float4*)(W + half * 64 * 128);
        for (int i = tid; i < 2048; i += 256) Ws4[i] = W4[i];
        __syncthreads();
        #pragma unroll 8
        for (int k = 0; k < 64; ++k) {
            float4 w = Ws4[k * 32 + fgrp];
            float x0 = Xs[n0 * 128 + half * 64 + k];
            float x1 = Xs[n0 * 128 + 128 + half * 64 + k];
            acc0.x += x0 * w.x; acc0.y += x0 * w.y; acc0.z += x0 * w.z; acc0.w += x0 * w.w;
            acc1.x += x1 * w.x; acc1.y += x1 * w.y; acc1.z += x1 * w.z; acc1.w += x1 * w.w;
        }
    }
    float4* H4 = (float4*)(H + base * 128);
    H4[n0 * 32 + fgrp] = acc0;
    H4[(n0 + 1) * 32 + fgrp] = acc1;
}

// ---------------- per-node attention scalars a_s = h.a_src, a_d = h.a_dst ----------------
__global__ __launch_bounds__(256) void av_kernel(const float* __restrict__ H,
                                                 const float* __restrict__ a_src,
                                                 const float* __restrict__ a_dst,
                                                 float* __restrict__ as_out,
                                                 float* __restrict__ ad_out, int N) {
    int gid = blockIdx.x * blockDim.x + threadIdx.x;
    int n = gid >> 6, lane = gid & 63;
    if (n >= N) return;
    float2 hv = ((const float2*)H)[(long)n * 64 + lane];
    float2 av = ((const float2*)a_src)[lane];
    float2 dv = ((const float2*)a_dst)[lane];
    float ps = hv.x * av.x + hv.y * av.y;
    float pd = hv.x * dv.x + hv.y * dv.y;
    for (int off = 32; off; off >>= 1) {
        ps += __shfl_xor(ps, off);
        pd += __shfl_xor(pd, off);
    }
    if (lane == 0) { as_out[n] = ps; ad_out[n] = pd; }
}

// ---------------- CSR build: histogram, 2-level scan, placement ----------------
__global__ __launch_bounds__(256) void hist_kernel(const int* __restrict__ dst, int E, int total,
                                                   int* __restrict__ deg) {
    int i = blockIdx.x * blockDim.x + threadIdx.x;
    if (i >= total) return;
    int d = (i < E) ? dst[i] : (i - E);  // self-loops appended
    atomicAdd(&deg[d], 1);
}

__global__ __launch_bounds__(256) void scan1_kernel(const int* __restrict__ deg, int n,
                                                    int* __restrict__ bsum) {
    __shared__ int s[256];
    int i = blockIdx.x * 256 + threadIdx.x;
    s[threadIdx.x] = (i < n) ? deg[i] : 0;
    __syncthreads();
    for (int off = 128; off; off >>= 1) {
        if (threadIdx.x < off) s[threadIdx.x] += s[threadIdx.x + off];
        __syncthreads();
    }
    if (threadIdx.x == 0) bsum[blockIdx.x] = s[0];
}

__global__ void scan2_kernel(int* __restrict__ bsum, int nb, int* __restrict__ offs, int n) {
    if (threadIdx.x == 0 && blockIdx.x == 0) {
        int acc = 0;
        for (int i = 0; i < nb; ++i) { int v = bsum[i]; bsum[i] = acc; acc += v; }
        offs[n] = acc;
    }
}

// exclusive scan within block + block offset; writes offs[i], and deg[i] becomes cursor copy
__global__ __launch_bounds__(256) void scan3_kernel(int* __restrict__ deg, int n,
                                                    const int* __restrict__ bsum,
                                                    int* __restrict__ offs) {
    __shared__ int s[256];
    int i = blockIdx.x * 256 + threadIdx.x;
    int v = (i < n) ? deg[i] : 0;
    s[threadIdx.x] = v;
    __syncthreads();
    for (int off = 1; off < 256; off <<= 1) {
        int t = (threadIdx.x >= off) ? s[threadIdx.x - off] : 0;
        __syncthreads();
        s[threadIdx.x] += t;
        __syncthreads();
    }
    if (i < n) {
        int excl = s[threadIdx.x] - v + bsum[blockIdx.x];
        offs[i] = excl;
        deg[i] = excl;  // cursor for placement
    }
}

__global__ __launch_bounds__(256) void place_kernel(const int* __restrict__ src,
                                                    const int* __restrict__ dst, int E, int total,
                                                    int* __restrict__ cursor,
                                                    int* __restrict__ slot) {
    int i = blockIdx.x * blockDim.x + threadIdx.x;
    if (i >= total) return;
    int s = (i < E) ? src[i] : (i - E);
    int d = (i < E) ? dst[i] : (i - E);
    int pos = atomicAdd(&cursor[d], 1);
    slot[pos] = s;
}

// ---------------- pull aggregation: out[n] = elu( (sum_e e*h[src]) / (sum_e e) + bias ) --------
__global__ __launch_bounds__(256) void pull_kernel(const float* __restrict__ H,
                                                   const float* __restrict__ a_s,
                                                   const float* __restrict__ a_d,
                                                   const int* __restrict__ offs,
                                                   const int* __restrict__ slot,
                                                   const float* __restrict__ bias,
                                                   float* __restrict__ out, int N) {
    int gid = blockIdx.x * blockDim.x + threadIdx.x;
    int n = gid >> 6, lane = gid & 63;
    if (n >= N) return;
    int beg = offs[n], end = offs[n + 1];
    float ad = a_d[n];
    float2 acc = {0.f, 0.f};
    float ssum = 0.f;
    for (int k = beg; k < end; ++k) {
        int s = slot[k];
        float e = expf(lrelu(a_s[s] + ad));  // no max-subtract needed: alpha identical
        float2 hv = ((const float2*)H)[(long)s * 64 + lane];
        acc.x += e * hv.x;
        acc.y += e * hv.y;
        ssum += e;
    }
    float inv = 1.f / ssum;  // >= 1 self-loop always present
    float2 b = ((const float2*)bias)[lane];
    float ox = acc.x * inv + b.x;
    float oy = acc.y * inv + b.y;
    ox = ox > 0.f ? ox : expm1f(ox);
    oy = oy > 0.f ? oy : expm1f(oy);
    ((float2*)out)[(long)n * 64 + lane] = make_float2(ox, oy);
}

// ---------------- adjacent-group mean ----------------
__global__ __launch_bounds__(256) void adj_kernel(const int* __restrict__ gsrc,
                                                  const int* __restrict__ gdst, int Eg,
                                                  const float* __restrict__ gx,
                                                  float* __restrict__ adj_sum,
                                                  float* __restrict__ cnt) {
    int gid = blockIdx.x * blockDim.x + threadIdx.x;
    int i = gid >> 6, lane = gid & 63;
    if (i >= Eg) return;
    int s = gsrc[i], d = gdst[i];
    float2 gv = ((const float2*)gx)[(long)d * 64 + lane];
    atomicAdd(&adj_sum[(long)s * 128 + 2 * lane], gv.x);
    atomicAdd(&adj_sum[(long)s * 128 + 2 * lane + 1], gv.y);
    if (lane == 0) atomicAdd(&cnt[s], 1.f);
}

__global__ __launch_bounds__(256) void adjdiv_kernel(const float* __restrict__ adj_sum,
                                                     const float* __restrict__ cnt,
                                                     float* __restrict__ adj_mean, int G) {
    int gid = blockIdx.x * blockDim.x + threadIdx.x;
    int g = gid >> 6, lane = gid & 63;
    if (g >= G) return;
    float inv = 1.f / fmaxf(cnt[g], 1.f);
    float2 v = ((const float2*)adj_sum)[(long)g * 64 + lane];
    ((float2*)adj_mean)[(long)g * 64 + lane] = make_float2(v.x * inv, v.y * inv);
}

// ---------------- final: interaction + in-place updated + FC 128->16 ----------------
__global__ __launch_bounds__(256) void final_kernel(const int* __restrict__ node_group,
                                                    const float* __restrict__ gx,
                                                    const float* __restrict__ adj_mean,
                                                    const float* __restrict__ fcW,
                                                    const float* __restrict__ fcb,
                                                    float* __restrict__ upd,  // in: fullx_elu
                                                    float* __restrict__ out, int N) {
    int gid = blockIdx.x * blockDim.x + threadIdx.x;
    int n = gid >> 6, lane = gid & 63;
    if (n >= N) return;
    int g = node_group[n];
    float2 row = ((const float2*)upd)[(long)n * 64 + lane];
    float2 gf = ((const float2*)gx)[(long)g * 64 + lane];
    float2 am = ((const float2*)adj_mean)[(long)g * 64 + lane];
    float pg = row.x * gf.x + row.y * gf.y;
    float pa = row.x * am.x + row.y * am.y;
    for (int off = 32; off; off >>= 1) {
        pg += __shfl_xor(pg, off);
        pa += __shfl_xor(pa, off);
    }
    float ux = row.x + pg * gf.x + pa * am.x;
    float uy = row.y + pg * gf.y + pa * am.y;
    ((float2*)upd)[(long)n * 64 + lane] = make_float2(ux, uy);
    // FC: p[c] = sum_j upd[j] * fcW[j][c]; this lane covers j = 2*lane, 2*lane+1
    float p[16];
    const float4* fW4 = (const float4*)fcW;  // row j -> 4 float4s
    #pragma unroll
    for (int q = 0; q < 4; ++q) {
        float4 w0 = fW4[(2 * lane) * 4 + q];
        float4 w1 = fW4[(2 * lane + 1) * 4 + q];
        p[4 * q + 0] = ux * w0.x + uy * w1.x;
        p[4 * q + 1] = ux * w0.y + uy * w1.y;
        p[4 * q + 2] = ux * w0.z + uy * w1.z;
        p[4 * q + 3] = ux * w0.w + uy * w1.w;
    }
    #pragma unroll
    for (int off = 32; off; off >>= 1) {
        #pragma unroll
        for (int c = 0; c < 16; ++c) p[c] += __shfl_xor(p[c], off);
    }
    if (lane == 0) {
        const float4* fb4 = (const float4*)fcb;
        float4* o4 = (float4*)(out + (long)n * 16);
        #pragma unroll
        for (int q = 0; q < 4; ++q) {
            float4 b = fb4[q];
            float4 o;
            o.x = p[4 * q + 0] + b.x;
            o.y = p[4 * q + 1] + b.y;
            o.z = p[4 * q + 2] + b.z;
            o.w = p[4 * q + 3] + b.w;
            o4[q] = o;
        }
    }
}

extern "C" void kernel_launch(void* const* d_in, const int* in_sizes, int n_in,
                              void* d_out, int out_size, void* d_ws, size_t ws_size,
                              hipStream_t stream) {
    const float* x_full = (const float*)d_in[0];
    const float* x_group = (const float*)d_in[1];
    const float* W_full = (const float*)d_in[2];
    const float* a_src_full = (const float*)d_in[3];
    const float* a_dst_full = (const float*)d_in[4];
    const float* bias_full = (const float*)d_in[5];
    const float* W_group = (const float*)d_in[6];
    const float* a_src_g = (const float*)d_in[7];
    const float* a_dst_g = (const float*)d_in[8];
    const float* bias_g = (const float*)d_in[9];
    const float* fc_W = (const float*)d_in[10];
    const float* fc_b = (const float*)d_in[11];
    const int* ef = (const int*)d_in[12];
    const int* eg = (const int*)d_in[13];
    const int* node_group = (const int*)d_in[14];

    int N = in_sizes[0] / 128;
    int G = in_sizes[1] / 128;
    int E = in_sizes[12] / 2;
    int Eg = in_sizes[13] / 2;
    const int* ef_src = ef;
    const int* ef_dst = ef + E;
    const int* eg_src = eg;
    const int* eg_dst = eg + Eg;

    float* out_cls = (float*)d_out;
    float* fx = out_cls + (long)N * 16;  // fullx_elu scratch, becomes `updated`

    char* w = (char*)d_ws;
    auto alloc = [&](size_t bytes) {
        char* p = w;
        w += (bytes + 255) & ~(size_t)255;
        return p;
    };
    float* h_full = (float*)alloc((size_t)N * 128 * 4);
    float* a_s = (float*)alloc((size_t)N * 4);
    float* a_d = (float*)alloc((size_t)N * 4);
    float* h_g = (float*)alloc((size_t)G * 128 * 4);
    float* a_sg = (float*)alloc((size_t)G * 4);
    float* a_dg = (float*)alloc((size_t)G * 4);
    float* gx = (float*)alloc((size_t)G * 128 * 4);
    float* adj_sum = (float*)alloc((size_t)G * 128 * 4);
    float* adj_mean = (float*)alloc((size_t)G * 128 * 4);
    float* cnt = (float*)alloc((size_t)G * 4);
    int* deg_f = (int*)alloc((size_t)N * 4);
    int* offs_f = (int*)alloc((size_t)(N + 1) * 4);
    int* slot_f = (int*)alloc((size_t)(E + N) * 4);
    int* deg_g = (int*)alloc((size_t)G * 4);
    int* offs_g = (int*)alloc((size_t)(G + 1) * 4);
    int* slot_g = (int*)alloc((size_t)(Eg + G) * 4);
    int* bsum = (int*)alloc(256 * 4);
    int* bsum_g = (int*)alloc(256 * 4);

    (void)hipMemsetAsync(deg_f, 0, (size_t)N * 4, stream);
    (void)hipMemsetAsync(deg_g, 0, (size_t)G * 4, stream);
    (void)hipMemsetAsync(adj_sum, 0, (size_t)G * 128 * 4, stream);
    (void)hipMemsetAsync(cnt, 0, (size_t)G * 4, stream);

    auto cdiv = [](int a, int b) { return (a + b - 1) / b; };

    // feature transforms
    gemm128_kernel<<<N / 16, 256, 0, stream>>>(x_full, W_full, h_full, N);
    gemm128_kernel<<<G / 16, 256, 0, stream>>>(x_group, W_group, h_g, G);
    av_kernel<<<cdiv(N * 64, 256), 256, 0, stream>>>(h_full, a_src_full, a_dst_full, a_s, a_d, N);
    av_kernel<<<cdiv(G * 64, 256), 256, 0, stream>>>(h_g, a_src_g, a_dst_g, a_sg, a_dg, G);

    // full graph CSR + pull
    int totF = E + N;
    int nbF = cdiv(N, 256);
    hist_kernel<<<cdiv(totF, 256), 256, 0, stream>>>(ef_dst, E, totF, deg_f);
    scan1_kernel<<<nbF, 256, 0, stream>>>(deg_f, N, bsum);
    scan2_kernel<<<1, 64, 0, stream>>>(bsum, nbF, offs_f, N);
    scan3_kernel<<<nbF, 256, 0, stream>>>(deg_f, N, bsum, offs_f);
    place_kernel<<<cdiv(totF, 256), 256, 0, stream>>>(ef_src, ef_dst, E, totF, deg_f, slot_f);
    pull_kernel<<<cdiv(N * 64, 256), 256, 0, stream>>>(h_full, a_s, a_d, offs_f, slot_f,
                                                       bias_full, fx, N);

    // group graph CSR + pull
    int totG = Eg + G;
    int nbG = cdiv(G, 256);
    hist_kernel<<<cdiv(totG, 256), 256, 0, stream>>>(eg_dst, Eg, totG, deg_g);
    scan1_kernel<<<nbG, 256, 0, stream>>>(deg_g, G, bsum_g);
    scan2_kernel<<<1, 64, 0, stream>>>(bsum_g, nbG, offs_g, G);
    scan3_kernel<<<nbG, 256, 0, stream>>>(deg_g, G, bsum_g, offs_g);
    place_kernel<<<cdiv(totG, 256), 256, 0, stream>>>(eg_src, eg_dst, Eg, totG, deg_g, slot_g);
    pull_kernel<<<cdiv(G * 64, 256), 256, 0, stream>>>(h_g, a_sg, a_dg, offs_g, slot_g,
                                                       bias_g, gx, G);

    // adjacent-group mean
    adj_kernel<<<cdiv(Eg * 64, 256), 256, 0, stream>>>(eg_src, eg_dst, Eg, gx, adj_sum, cnt);
    adjdiv_kernel<<<cdiv(G * 64, 256), 256, 0, stream>>>(adj_sum, cnt, adj_mean, G);

    // final fused interaction + FC
    final_kernel<<<cdiv(N * 64, 256), 256, 0, stream>>>(node_group, gx, adj_mean, fc_W, fc_b,
                                                        fx, out_cls, N);
}

// Round 5
// 329.548 us; speedup vs baseline: 1.2348x; 1.2348x over previous
//
#include <hip/hip_runtime.h>

typedef unsigned short u16;
typedef unsigned int u32;

static __device__ __forceinline__ float lrelu(float x) { return x >= 0.f ? x : 0.2f * x; }

// f32 -> bf16 round-to-nearest-even (bit trick; no NaN in this workload)
static __device__ __forceinline__ u16 f2bf(float f) {
    u32 u = __float_as_uint(f);
    u += 0x7FFF + ((u >> 16) & 1);
    return (u16)(u >> 16);
}
static __device__ __forceinline__ float bf2f(u16 h) {
    return __uint_as_float((u32)h << 16);
}

// ---------------- GEMM: Hb[N][128](bf16) = X[N][128] @ W[128][128]; fused a_s/a_d ----------
__global__ __launch_bounds__(256) void gemm128_kernel(const float* __restrict__ X,
                                                      const float* __restrict__ W,
                                                      const float* __restrict__ a_src,
                                                      const float* __restrict__ a_dst,
                                                      u16* __restrict__ Hb,
                                                      float* __restrict__ as_out,
                                                      float* __restrict__ ad_out, int N) {
    __shared__ float Ws[64 * 128];   // 32 KB (half of W)
    __shared__ float Xs[32 * 128];   // 16 KB (32 node rows)
    int tid = threadIdx.x;
    long base = (long)blockIdx.x * 32;
    float4* Ws4 = (float4*)Ws;
    float4* Xs4 = (float4*)Xs;
    const float4* X4 = (const float4*)(X + base * 128);
    for (int i = tid; i < 1024; i += 256) {
        int r = i >> 5;
        Xs4[i] = (base + r < N) ? X4[i] : make_float4(0.f, 0.f, 0.f, 0.f);
    }
    int fgrp = tid & 31;        // feature float4 index (0..31)
    int n0 = (tid >> 5) * 4;    // local node quad (0..28)
    float4 acc[4] = {};
    for (int half = 0; half < 2; ++half) {
        __syncthreads();  // Xs ready (half0) / previous compute done (half1)
        const float4* W4 = (const float4*)(W + half * 64 * 128);
        for (int i = tid; i < 2048; i += 256) Ws4[i] = W4[i];
        __syncthreads();
        #pragma unroll 4
        for (int kk = 0; kk < 64; ++kk) {
            float4 w = Ws4[kk * 32 + fgrp];
            #pragma unroll
            for (int j = 0; j < 4; ++j) {
                float x = Xs[(n0 + j) * 128 + half * 64 + kk];
                acc[j].x += x * w.x; acc[j].y += x * w.y;
                acc[j].z += x * w.z; acc[j].w += x * w.w;
            }
        }
    }
    // fused attention scalars: reduce over the 32 lanes sharing each node quad
    float4 as4 = ((const float4*)a_src)[fgrp];
    float4 ad4 = ((const float4*)a_dst)[fgrp];
    float ps[4], pd[4];
    #pragma unroll
    for (int j = 0; j < 4; ++j) {
        ps[j] = acc[j].x * as4.x + acc[j].y * as4.y + acc[j].z * as4.z + acc[j].w * as4.w;
        pd[j] = acc[j].x * ad4.x + acc[j].y * ad4.y + acc[j].z * ad4.z + acc[j].w * ad4.w;
    }
    #pragma unroll
    for (int off = 16; off; off >>= 1) {
        #pragma unroll
        for (int j = 0; j < 4; ++j) {
            ps[j] += __shfl_xor(ps[j], off);
            pd[j] += __shfl_xor(pd[j], off);
        }
    }
    if ((tid & 31) == 0) {
        #pragma unroll
        for (int j = 0; j < 4; ++j) {
            long n = base + n0 + j;
            if (n < N) { as_out[n] = ps[j]; ad_out[n] = pd[j]; }
        }
    }
    #pragma unroll
    for (int j = 0; j < 4; ++j) {
        long n = base + n0 + j;
        if (n < N) {
            ushort4 hv;
            hv.x = f2bf(acc[j].x); hv.y = f2bf(acc[j].y);
            hv.z = f2bf(acc[j].z); hv.w = f2bf(acc[j].w);
            ((ushort4*)(Hb + n * 128))[fgrp] = hv;
        }
    }
}

// ---------------- merged CSR build over both graphs ----------------
// deg/offs layout: [0,N) full nodes, [N,Npad) zero pad, [Npad,Npad+G) group nodes
__global__ __launch_bounds__(256) void hist2_kernel(const int* __restrict__ efd, int E, int N,
                                                    const int* __restrict__ egd, int Eg, int G,
                                                    int Npad, int* __restrict__ deg) {
    int i = blockIdx.x * 256 + threadIdx.x;
    int totF = E + N;
    int tot = totF + Eg + G;
    if (i >= tot) return;
    int d;
    if (i < E) d = efd[i];
    else if (i < totF) d = i - E;
    else {
        int j = i - totF;
        d = Npad + ((j < Eg) ? egd[j] : (j - Eg));
    }
    atomicAdd(&deg[d], 1);
}

__global__ __launch_bounds__(256) void scan1_kernel(const int* __restrict__ deg, int n,
                                                    int* __restrict__ bsum) {
    __shared__ int s[256];
    int i = blockIdx.x * 256 + threadIdx.x;
    s[threadIdx.x] = (i < n) ? deg[i] : 0;
    __syncthreads();
    for (int off = 128; off; off >>= 1) {
        if (threadIdx.x < off) s[threadIdx.x] += s[threadIdx.x + off];
        __syncthreads();
    }
    if (threadIdx.x == 0) bsum[blockIdx.x] = s[0];
}

// parallel exclusive scan of block sums (nb <= 256), one block
__global__ __launch_bounds__(256) void scan2_kernel(int* __restrict__ bsum, int nb,
                                                    int* __restrict__ offs, int Ltot) {
    __shared__ int s[256];
    int t = threadIdx.x;
    int v = (t < nb) ? bsum[t] : 0;
    s[t] = v;
    __syncthreads();
    for (int off = 1; off < 256; off <<= 1) {
        int u = (t >= off) ? s[t - off] : 0;
        __syncthreads();
        s[t] += u;
        __syncthreads();
    }
    if (t < nb) bsum[t] = s[t] - v;      // exclusive
    if (t == nb - 1) offs[Ltot] = s[t];  // grand total
}

__global__ __launch_bounds__(256) void scan3_kernel(int* __restrict__ deg, int n,
                                                    const int* __restrict__ bsum,
                                                    int* __restrict__ offs) {
    __shared__ int s[256];
    int i = blockIdx.x * 256 + threadIdx.x;
    int v = (i < n) ? deg[i] : 0;
    s[threadIdx.x] = v;
    __syncthreads();
    for (int off = 1; off < 256; off <<= 1) {
        int t = (threadIdx.x >= off) ? s[threadIdx.x - off] : 0;
        __syncthreads();
        s[threadIdx.x] += t;
        __syncthreads();
    }
    if (i < n) {
        int excl = s[threadIdx.x] - v + bsum[blockIdx.x];
        offs[i] = excl;
        deg[i] = excl;  // cursor for placement
    }
}

// placement + per-edge attention weight e = exp(lrelu(a_s[src]+a_d[dst])) computed ONCE
__global__ __launch_bounds__(256) void place2_kernel(const int* __restrict__ efs,
                                                     const int* __restrict__ efd, int E, int N,
                                                     const int* __restrict__ egs,
                                                     const int* __restrict__ egd, int Eg, int G,
                                                     int Npad,
                                                     const float* __restrict__ a_s,
                                                     const float* __restrict__ a_d,
                                                     const float* __restrict__ a_sg,
                                                     const float* __restrict__ a_dg,
                                                     int* __restrict__ cursor,
                                                     int* __restrict__ slot,
                                                     float* __restrict__ eslot) {
    int i = blockIdx.x * 256 + threadIdx.x;
    int totF = E + N;
    int tot = totF + Eg + G;
    if (i >= tot) return;
    int s, d, dcur;
    float av;
    if (i < totF) {
        if (i < E) { s = efs[i]; d = efd[i]; } else { s = d = i - E; }
        av = a_s[s] + a_d[d];
        dcur = d;
    } else {
        int j = i - totF;
        if (j < Eg) { s = egs[j]; d = egd[j]; } else { s = d = j - Eg; }
        av = a_sg[s] + a_dg[d];
        dcur = Npad + d;
    }
    float e = expf(lrelu(av));  // max-subtract skipped: alpha unchanged, no overflow (|av|<~10)
    int pos = atomicAdd(&cursor[dcur], 1);
    slot[pos] = s;
    eslot[pos] = e;
}

// ---------------- pull aggregation (both graphs): out = elu(sum(e*h)/sum(e) + bias) --------
__global__ __launch_bounds__(256) void pull2_kernel(const u16* __restrict__ Hf,
                                                    const u16* __restrict__ Hg,
                                                    const int* __restrict__ offs,
                                                    const int* __restrict__ slot,
                                                    const float* __restrict__ eslot,
                                                    const float* __restrict__ bias_f,
                                                    const float* __restrict__ bias_g,
                                                    float* __restrict__ fx,
                                                    float* __restrict__ gx,
                                                    int N, int G, int Npad) {
    int gid = blockIdx.x * 256 + threadIdx.x;
    int w = gid >> 6, lane = gid & 63;
    const u16* H;
    const float* bias;
    float* out;
    int idx;
    if (w < N) {
        H = Hf; bias = bias_f; out = fx + (long)w * 128; idx = w;
    } else if (w < N + G) {
        int g = w - N;
        H = Hg; bias = bias_g; out = gx + (long)g * 128; idx = Npad + g;
    } else return;
    int beg = offs[idx], end = offs[idx + 1];
    float accx = 0.f, accy = 0.f, ssum = 0.f;
    int k = beg;
    for (; k + 2 <= end; k += 2) {  // 2-way unroll: two gathers in flight
        int s0 = slot[k], s1 = slot[k + 1];
        float e0 = eslot[k], e1 = eslot[k + 1];
        ushort2 h0 = ((const ushort2*)H)[(long)s0 * 64 + lane];
        ushort2 h1 = ((const ushort2*)H)[(long)s1 * 64 + lane];
        accx += e0 * bf2f(h0.x) + e1 * bf2f(h1.x);
        accy += e0 * bf2f(h0.y) + e1 * bf2f(h1.y);
        ssum += e0 + e1;
    }
    if (k < end) {
        int s0 = slot[k];
        float e0 = eslot[k];
        ushort2 h0 = ((const ushort2*)H)[(long)s0 * 64 + lane];
        accx += e0 * bf2f(h0.x);
        accy += e0 * bf2f(h0.y);
        ssum += e0;
    }
    float inv = 1.f / ssum;  // >= 1 self-loop always present
    float2 b = ((const float2*)bias)[lane];
    float ox = accx * inv + b.x;
    float oy = accy * inv + b.y;
    ox = ox > 0.f ? ox : expm1f(ox);
    oy = oy > 0.f ? oy : expm1f(oy);
    ((float2*)out)[lane] = make_float2(ox, oy);
}

// ---------------- adjacent-group sum (atomics; tiny graph) ----------------
__global__ __launch_bounds__(256) void adj_kernel(const int* __restrict__ gsrc,
                                                  const int* __restrict__ gdst, int Eg,
                                                  const float* __restrict__ gx,
                                                  float* __restrict__ adj_sum,
                                                  float* __restrict__ cnt) {
    int gid = blockIdx.x * 256 + threadIdx.x;
    int i = gid >> 6, lane = gid & 63;
    if (i >= Eg) return;
    int s = gsrc[i], d = gdst[i];
    float2 gv = ((const float2*)gx)[(long)d * 64 + lane];
    atomicAdd(&adj_sum[(long)s * 128 + 2 * lane], gv.x);
    atomicAdd(&adj_sum[(long)s * 128 + 2 * lane + 1], gv.y);
    if (lane == 0) atomicAdd(&cnt[s], 1.f);
}

// ---------------- final: interaction + in-place updated + FC 128->16 ----------------
__global__ __launch_bounds__(256) void final_kernel(const int* __restrict__ node_group,
                                                    const float* __restrict__ gx,
                                                    const float* __restrict__ adj_sum,
                                                    const float* __restrict__ cnt,
                                                    const float* __restrict__ fcW,
                                                    const float* __restrict__ fcb,
                                                    float* __restrict__ upd,  // in: fullx_elu
                                                    float* __restrict__ out, int N) {
    int gid = blockIdx.x * 256 + threadIdx.x;
    int n = gid >> 6, lane = gid & 63;
    if (n >= N) return;
    int g = node_group[n];
    float2 row = ((const float2*)upd)[(long)n * 64 + lane];
    float2 gf = ((const float2*)gx)[(long)g * 64 + lane];
    float inv_cnt = 1.f / fmaxf(cnt[g], 1.f);
    float2 amv = ((const float2*)adj_sum)[(long)g * 64 + lane];
    float amx = amv.x * inv_cnt, amy = amv.y * inv_cnt;
    float pg = row.x * gf.x + row.y * gf.y;
    float pa = row.x * amx + row.y * amy;
    for (int off = 32; off; off >>= 1) {
        pg += __shfl_xor(pg, off);
        pa += __shfl_xor(pa, off);
    }
    float ux = row.x + pg * gf.x + pa * amx;
    float uy = row.y + pg * gf.y + pa * amy;
    ((float2*)upd)[(long)n * 64 + lane] = make_float2(ux, uy);
    float p[16];
    const float4* fW4 = (const float4*)fcW;
    #pragma unroll
    for (int q = 0; q < 4; ++q) {
        float4 w0 = fW4[(2 * lane) * 4 + q];
        float4 w1 = fW4[(2 * lane + 1) * 4 + q];
        p[4 * q + 0] = ux * w0.x + uy * w1.x;
        p[4 * q + 1] = ux * w0.y + uy * w1.y;
        p[4 * q + 2] = ux * w0.z + uy * w1.z;
        p[4 * q + 3] = ux * w0.w + uy * w1.w;
    }
    #pragma unroll
    for (int off = 32; off; off >>= 1) {
        #pragma unroll
        for (int c = 0; c < 16; ++c) p[c] += __shfl_xor(p[c], off);
    }
    if (lane == 0) {
        const float4* fb4 = (const float4*)fcb;
        float4* o4 = (float4*)(out + (long)n * 16);
        #pragma unroll
        for (int q = 0; q < 4; ++q) {
            float4 b = fb4[q];
            float4 o;
            o.x = p[4 * q + 0] + b.x;
            o.y = p[4 * q + 1] + b.y;
            o.z = p[4 * q + 2] + b.z;
            o.w = p[4 * q + 3] + b.w;
            o4[q] = o;
        }
    }
}

extern "C" void kernel_launch(void* const* d_in, const int* in_sizes, int n_in,
                              void* d_out, int out_size, void* d_ws, size_t ws_size,
                              hipStream_t stream) {
    const float* x_full = (const float*)d_in[0];
    const float* x_group = (const float*)d_in[1];
    const float* W_full = (const float*)d_in[2];
    const float* a_src_full = (const float*)d_in[3];
    const float* a_dst_full = (const float*)d_in[4];
    const float* bias_full = (const float*)d_in[5];
    const float* W_group = (const float*)d_in[6];
    const float* a_src_g = (const float*)d_in[7];
    const float* a_dst_g = (const float*)d_in[8];
    const float* bias_g = (const float*)d_in[9];
    const float* fc_W = (const float*)d_in[10];
    const float* fc_b = (const float*)d_in[11];
    const int* ef = (const int*)d_in[12];
    const int* eg = (const int*)d_in[13];
    const int* node_group = (const int*)d_in[14];

    int N = in_sizes[0] / 128;
    int G = in_sizes[1] / 128;
    int E = in_sizes[12] / 2;
    int Eg = in_sizes[13] / 2;
    const int* ef_src = ef;
    const int* ef_dst = ef + E;
    const int* eg_src = eg;
    const int* eg_dst = eg + Eg;

    int Npad = (N + 255) & ~255;
    int Ltot = Npad + G;       // deg/offs logical length (multiple of 256 when G%256==0)
    int LtotPad = (Ltot + 255) & ~255;
    int totF = E + N;
    int tot = totF + Eg + G;

    float* out_cls = (float*)d_out;
    float* fx = out_cls + (long)N * 16;  // fullx_elu scratch, becomes `updated`

    char* w = (char*)d_ws;
    auto alloc = [&](size_t bytes) {
        char* p = w;
        w += (bytes + 255) & ~(size_t)255;
        return p;
    };
    u16* h_full = (u16*)alloc((size_t)N * 128 * 2);
    u16* h_g = (u16*)alloc((size_t)G * 128 * 2);
    float* a_s = (float*)alloc((size_t)N * 4);
    float* a_d = (float*)alloc((size_t)N * 4);
    float* a_sg = (float*)alloc((size_t)G * 4);
    float* a_dg = (float*)alloc((size_t)G * 4);
    float* gx = (float*)alloc((size_t)G * 128 * 4);
    float* adj_sum = (float*)alloc((size_t)G * 128 * 4);   // contiguous with cnt
    float* cnt = (float*)alloc((size_t)G * 4);
    int* deg = (int*)alloc((size_t)LtotPad * 4);
    int* offs = (int*)alloc((size_t)(LtotPad + 1) * 4);
    int* slot = (int*)alloc((size_t)tot * 4);
    float* eslot = (float*)alloc((size_t)tot * 4);
    int* bsum = (int*)alloc(256 * 4);

    (void)hipMemsetAsync(deg, 0, (size_t)LtotPad * 4, stream);
    (void)hipMemsetAsync(adj_sum, 0, (size_t)G * 128 * 4 + (size_t)G * 4, stream);

    auto cdiv = [](int a, int b) { return (a + b - 1) / b; };

    // feature transforms + fused attention scalars
    gemm128_kernel<<<cdiv(N, 32), 256, 0, stream>>>(x_full, W_full, a_src_full, a_dst_full,
                                                    h_full, a_s, a_d, N);
    gemm128_kernel<<<cdiv(G, 32), 256, 0, stream>>>(x_group, W_group, a_src_g, a_dst_g,
                                                    h_g, a_sg, a_dg, G);

    // merged CSR build
    int nb = cdiv(Ltot, 256);
    hist2_kernel<<<cdiv(tot, 256), 256, 0, stream>>>(ef_dst, E, N, eg_dst, Eg, G, Npad, deg);
    scan1_kernel<<<nb, 256, 0, stream>>>(deg, Ltot, bsum);
    scan2_kernel<<<1, 256, 0, stream>>>(bsum, nb, offs, Ltot);
    scan3_kernel<<<nb, 256, 0, stream>>>(deg, Ltot, bsum, offs);
    place2_kernel<<<cdiv(tot, 256), 256, 0, stream>>>(ef_src, ef_dst, E, N, eg_src, eg_dst,
                                                      Eg, G, Npad, a_s, a_d, a_sg, a_dg,
                                                      deg, slot, eslot);

    // pull aggregation for both graphs
    pull2_kernel<<<cdiv((N + G) * 64, 256), 256, 0, stream>>>(h_full, h_g, offs, slot, eslot,
                                                              bias_full, bias_g, fx, gx,
                                                              N, G, Npad);

    // adjacent-group sum + final fused interaction/FC (division folded into final)
    adj_kernel<<<cdiv(Eg * 64, 256), 256, 0, stream>>>(eg_src, eg_dst, Eg, gx, adj_sum, cnt);
    final_kernel<<<cdiv(N * 64, 256), 256, 0, stream>>>(node_group, gx, adj_sum, cnt, fc_W,
                                                        fc_b, fx, out_cls, N);
}